// Round 2
// baseline (678.291 us; speedup 1.0000x reference)
//
#include <hip/hip_runtime.h>
#include <hip/hip_bf16.h>

typedef __attribute__((ext_vector_type(8))) __bf16 bf16x8;
typedef __attribute__((ext_vector_type(4))) __bf16 bf16x4;
typedef __attribute__((ext_vector_type(4))) float f32x4;

#define MFMA16(a, b, c) __builtin_amdgcn_mfma_f32_16x16x32_bf16(a, b, c, 0, 0, 0)

static __device__ __forceinline__ ushort f2b(float f) {
    __bf16 b = (__bf16)f;
    return __builtin_bit_cast(ushort, b);
}
static __device__ __forceinline__ float b2f(ushort u) {
    __bf16 b = __builtin_bit_cast(__bf16, u);
    return (float)b;
}

// ---------------- f32 -> bf16 convert (vectorized) ----------------
__global__ void f32_to_bf16_k(const float* __restrict__ in, ushort* __restrict__ out, int n4) {
    int i = blockIdx.x * blockDim.x + threadIdx.x;
    if (i >= n4) return;
    float4 v = reinterpret_cast<const float4*>(in)[i];
    ushort4 o;
    o.x = f2b(v.x); o.y = f2b(v.y); o.z = f2b(v.z); o.w = f2b(v.w);
    reinterpret_cast<ushort4*>(out)[i] = o;
}

// ---------------- W [K][N] f32  ->  Wt [N][K] bf16 ----------------
__global__ void transpose_w_k(const float* __restrict__ W, ushort* __restrict__ Wt, int K, int N) {
    int idx = blockIdx.x * blockDim.x + threadIdx.x;
    if (idx >= K * N) return;
    int n = idx / K, k = idx - n * K;
    Wt[idx] = f2b(W[(size_t)k * N + n]);
}

// ---------------- V [8192][512] -> Vt [32][64][2048] ----------------
__global__ void transpose_v_k(const ushort* __restrict__ V, ushort* __restrict__ Vt) {
    int idx = blockIdx.x * blockDim.x + threadIdx.x;
    if (idx >= 32 * 64 * 2048) return;
    int nn = idx & 2047;
    int d  = (idx >> 11) & 63;
    int bh = idx >> 17;
    int b = bh >> 3, h = bh & 7;
    Vt[idx] = V[((size_t)(b * 2048 + nn)) * 512 + h * 64 + d];
}

// ---------------- per-64-chunk l2 normalize (in place) ----------------
__global__ void l2norm_k(ushort* __restrict__ T, int nchunk) {
    int tid = blockIdx.x * blockDim.x + threadIdx.x;
    int chunk = tid >> 4;
    if (chunk >= nchunk) return;
    int part = tid & 15;
    ushort* p = T + (size_t)chunk * 64 + part * 4;
    ushort4 u = *reinterpret_cast<ushort4*>(p);
    float x0 = b2f(u.x), x1 = b2f(u.y), x2 = b2f(u.z), x3 = b2f(u.w);
    float ss = x0 * x0 + x1 * x1 + x2 * x2 + x3 * x3;
    ss += __shfl_xor(ss, 1);
    ss += __shfl_xor(ss, 2);
    ss += __shfl_xor(ss, 4);
    ss += __shfl_xor(ss, 8);
    float inv = 1.0f / fmaxf(sqrtf(ss), 1e-12f);
    u.x = f2b(x0 * inv); u.y = f2b(x1 * inv); u.z = f2b(x2 * inv); u.w = f2b(x3 * inv);
    *reinterpret_cast<ushort4*>(p) = u;
}

// ---------------- GEMM: C[M][N] = A[M][K](bf16) * Bt[N][K](bf16)^T ----------------
// wave computes 16 rows x 64 cols; direct global fragment loads (L1/L2-fed)
template <int F32OUT>
__global__ __launch_bounds__(256)
void gemm_bt_k(const ushort* __restrict__ A, const ushort* __restrict__ Bt,
               void* __restrict__ Cout, int M, int N, int K) {
    const int lane = threadIdx.x & 63;
    const int wave = threadIdx.x >> 6;
    const int l15 = lane & 15, g = lane >> 4;
    const int rbase = (blockIdx.x * 4 + wave) * 16;
    const int cbase = blockIdx.y * 64;
    const ushort* Ap = A + (size_t)(rbase + l15) * K + 8 * g;
    const ushort* Bp = Bt + (size_t)(cbase + l15) * K + 8 * g;
    f32x4 acc[4] = {{0,0,0,0},{0,0,0,0},{0,0,0,0},{0,0,0,0}};
    for (int k = 0; k < K; k += 32) {
        bf16x8 a = *reinterpret_cast<const bf16x8*>(Ap + k);
#pragma unroll
        for (int c = 0; c < 4; ++c) {
            bf16x8 bfr = *reinterpret_cast<const bf16x8*>(Bp + (size_t)(c * 16) * K + k);
            acc[c] = MFMA16(a, bfr, acc[c]);
        }
    }
#pragma unroll
    for (int c = 0; c < 4; ++c) {
#pragma unroll
        for (int r = 0; r < 4; ++r) {
            int row = rbase + 4 * g + r;
            int col = cbase + c * 16 + l15;
            if (F32OUT)
                reinterpret_cast<float*>(Cout)[(size_t)row * N + col] = acc[c][r];
            else
                reinterpret_cast<ushort*>(Cout)[(size_t)row * N + col] = f2b(acc[c][r]);
        }
    }
}

// ---------------- causal cosine-sim flash attention ----------------
// Q,K: [b*2048][512] bf16 (l2-normalized per 64-chunk); Vt: [bh][64][2048] bf16
// O: [b*2048][512] bf16.  One wave per 16 q rows. KVBLK=32.
__global__ __launch_bounds__(256)
void flash_attn_k(const ushort* __restrict__ Q, const ushort* __restrict__ K,
                  const ushort* __restrict__ Vt, ushort* __restrict__ O) {
    const int lane = threadIdx.x & 63;
    const int wave = threadIdx.x >> 6;
    const int l15 = lane & 15;
    const int g = lane >> 4;
    const int bh = blockIdx.y;
    const int b = bh >> 3, h = bh & 7;
    const int qt = blockIdx.x * 4 + wave;  // 0..127
    const int qbase = qt * 16;
    const int qr = qbase + l15;  // this lane's global q row (softmax row r = l15)

    const ushort* Qb = Q + (size_t)(b * 2048) * 512 + h * 64;
    const ushort* Kb = K + (size_t)(b * 2048) * 512 + h * 64;
    const ushort* Vb = Vt + (size_t)bh * 64 * 2048;

    // Q as B-operand frags: col=l15 -> q row, k=8g+i -> d
    bf16x8 qf0 = *reinterpret_cast<const bf16x8*>(Qb + (size_t)qr * 512 + 8 * g);
    bf16x8 qf1 = *reinterpret_cast<const bf16x8*>(Qb + (size_t)qr * 512 + 8 * g + 32);

    f32x4 acc[4] = {{0,0,0,0},{0,0,0,0},{0,0,0,0},{0,0,0,0}};  // O^T: acc[dblk], col=l15=r, row=4g+reg=d%16
    float m = -INFINITY, lsum = 0.0f;

    const int nkv = (qbase + 16 + 31) >> 5;
    for (int kb = 0; kb < nkv; ++kb) {
        const int kv = kb << 5;
        // S^T = mfma(K, Q): two 16-wide j tiles
        const ushort* k0 = Kb + (size_t)(kv + l15) * 512 + 8 * g;
        const ushort* k1 = Kb + (size_t)(kv + 16 + l15) * 512 + 8 * g;
        f32x4 s0 = {0,0,0,0}, s1 = {0,0,0,0};
        s0 = MFMA16(*reinterpret_cast<const bf16x8*>(k0), qf0, s0);
        s0 = MFMA16(*reinterpret_cast<const bf16x8*>(k0 + 32), qf1, s0);
        s1 = MFMA16(*reinterpret_cast<const bf16x8*>(k1), qf0, s1);
        s1 = MFMA16(*reinterpret_cast<const bf16x8*>(k1 + 32), qf1, s1);

        // scale + causal mask; lane holds j = kv + 16t + 4g + r for row qr
        float sv[8];
#pragma unroll
        for (int r = 0; r < 4; ++r) {
            int j0 = kv + 4 * g + r;
            int j1 = kv + 16 + 4 * g + r;
            sv[r]     = (j0 <= qr) ? s0[r] * 8.0f : -INFINITY;
            sv[4 + r] = (j1 <= qr) ? s1[r] * 8.0f : -INFINITY;
        }
        float mb = sv[0];
#pragma unroll
        for (int i = 1; i < 8; ++i) mb = fmaxf(mb, sv[i]);
        mb = fmaxf(mb, __shfl_xor(mb, 16));
        mb = fmaxf(mb, __shfl_xor(mb, 32));
        float mnew = fmaxf(m, mb);
        float alpha = __expf(m - mnew);

        float psum = 0.0f;
        bf16x8 pt;
#pragma unroll
        for (int i = 0; i < 8; ++i) {
            float p = __expf(sv[i] - mnew);
            psum += p;
            pt[i] = (__bf16)p;
        }
        psum += __shfl_xor(psum, 16);
        psum += __shfl_xor(psum, 32);
        lsum = lsum * alpha + psum;
        m = mnew;

#pragma unroll
        for (int d = 0; d < 4; ++d) {
            acc[d][0] *= alpha; acc[d][1] *= alpha;
            acc[d][2] *= alpha; acc[d][3] *= alpha;
        }

        // O^T += mfma(A=Vt frag, B=pt). A: row=l15 -> d%16, k slot 8g+i -> j
        // k slot j map: i<4 -> kv+4g+i ; i>=4 -> kv+16+4g+(i-4)  (matches pt packing)
#pragma unroll
        for (int d = 0; d < 4; ++d) {
            const ushort* vrow = Vb + (size_t)(d * 16 + l15) * 2048;
            bf16x4 v0 = *reinterpret_cast<const bf16x4*>(vrow + kv + 4 * g);
            bf16x4 v1 = *reinterpret_cast<const bf16x4*>(vrow + kv + 16 + 4 * g);
            bf16x8 vf;
            vf[0] = v0[0]; vf[1] = v0[1]; vf[2] = v0[2]; vf[3] = v0[3];
            vf[4] = v1[0]; vf[5] = v1[1]; vf[6] = v1[2]; vf[7] = v1[3];
            acc[d] = MFMA16(vf, pt, acc[d]);
        }
    }

    float inv = 1.0f / lsum;
    ushort* Ob = O + (size_t)(b * 2048 + qbase + l15) * 512 + h * 64;
#pragma unroll
    for (int d = 0; d < 4; ++d) {
        bf16x4 w;
#pragma unroll
        for (int r = 0; r < 4; ++r) w[r] = (__bf16)(acc[d][r] * inv);
        *reinterpret_cast<bf16x4*>(Ob + d * 16 + 4 * g) = w;
    }
}

extern "C" void kernel_launch(void* const* d_in, const int* in_sizes, int n_in,
                              void* d_out, int out_size, void* d_ws, size_t ws_size,
                              hipStream_t stream) {
    const float* x  = (const float*)d_in[0];
    const float* Wq = (const float*)d_in[1];
    const float* Wk = (const float*)d_in[2];
    const float* Wv = (const float*)d_in[3];
    const float* Wo = (const float*)d_in[4];
    float* out = (float*)d_out;

    char* ws = (char*)d_ws;
    ushort* xb  = (ushort*)ws; ws += (size_t)8192 * 1024 * 2;  // 16 MB
    ushort* Wqt = (ushort*)ws; ws += (size_t)512 * 1024 * 2;
    ushort* Wkt = (ushort*)ws; ws += (size_t)512 * 1024 * 2;
    ushort* Wvt = (ushort*)ws; ws += (size_t)512 * 1024 * 2;
    ushort* Wot = (ushort*)ws; ws += (size_t)1024 * 512 * 2;
    ushort* Qm  = (ushort*)ws; ws += (size_t)8192 * 512 * 2;
    ushort* Km  = (ushort*)ws; ws += (size_t)8192 * 512 * 2;
    ushort* Vm  = (ushort*)ws; ws += (size_t)8192 * 512 * 2;
    ushort* Vtm = (ushort*)ws; ws += (size_t)8192 * 512 * 2;
    ushort* Om  = xb;  // reuse: xb dead after QKV GEMMs

    f32_to_bf16_k<<<8192, 256, 0, stream>>>(x, xb, 2097152);
    transpose_w_k<<<2048, 256, 0, stream>>>(Wq, Wqt, 1024, 512);
    transpose_w_k<<<2048, 256, 0, stream>>>(Wk, Wkt, 1024, 512);
    transpose_w_k<<<2048, 256, 0, stream>>>(Wv, Wvt, 1024, 512);
    transpose_w_k<<<2048, 256, 0, stream>>>(Wo, Wot, 512, 1024);

    gemm_bt_k<0><<<dim3(128, 8), 256, 0, stream>>>(xb, Wqt, Qm, 8192, 512, 1024);
    gemm_bt_k<0><<<dim3(128, 8), 256, 0, stream>>>(xb, Wkt, Km, 8192, 512, 1024);
    gemm_bt_k<0><<<dim3(128, 8), 256, 0, stream>>>(xb, Wvt, Vm, 8192, 512, 1024);

    l2norm_k<<<4096, 256, 0, stream>>>(Qm, 65536);
    l2norm_k<<<4096, 256, 0, stream>>>(Km, 65536);

    transpose_v_k<<<16384, 256, 0, stream>>>(Vm, Vtm);

    flash_attn_k<<<dim3(32, 32), 256, 0, stream>>>(Qm, Km, Vtm, Om);

    gemm_bt_k<1><<<dim3(128, 16), 256, 0, stream>>>(Om, Wot, out, 8192, 1024, 512);
}

// Round 3
// 489.662 us; speedup vs baseline: 1.3852x; 1.3852x over previous
//
#include <hip/hip_runtime.h>
#include <hip/hip_bf16.h>

typedef __attribute__((ext_vector_type(8))) __bf16 bf16x8;
typedef __attribute__((ext_vector_type(4))) __bf16 bf16x4;
typedef __attribute__((ext_vector_type(4))) float f32x4;

#define MFMA16(a, b, c) __builtin_amdgcn_mfma_f32_16x16x32_bf16(a, b, c, 0, 0, 0)

static __device__ __forceinline__ ushort f2b(float f) {
    __bf16 b = (__bf16)f;
    return __builtin_bit_cast(ushort, b);
}
static __device__ __forceinline__ float b2f(ushort u) {
    __bf16 b = __builtin_bit_cast(__bf16, u);
    return (float)b;
}
static __device__ __forceinline__ bf16x8 cat44(bf16x4 a, bf16x4 b) {
    bf16x8 r;
    r[0] = a[0]; r[1] = a[1]; r[2] = a[2]; r[3] = a[3];
    r[4] = b[0]; r[5] = b[1]; r[6] = b[2]; r[7] = b[3];
    return r;
}

// ---------------- f32 -> bf16 convert (vectorized) ----------------
__global__ void f32_to_bf16_k(const float* __restrict__ in, ushort* __restrict__ out, int n4) {
    int i = blockIdx.x * blockDim.x + threadIdx.x;
    if (i >= n4) return;
    float4 v = reinterpret_cast<const float4*>(in)[i];
    ushort4 o;
    o.x = f2b(v.x); o.y = f2b(v.y); o.z = f2b(v.z); o.w = f2b(v.w);
    reinterpret_cast<ushort4*>(out)[i] = o;
}

// ---------------- W [K][N] f32  ->  Wt [N][K] bf16 ----------------
__global__ void transpose_w_k(const float* __restrict__ W, ushort* __restrict__ Wt, int K, int N) {
    int idx = blockIdx.x * blockDim.x + threadIdx.x;
    if (idx >= K * N) return;
    int n = idx / K, k = idx - n * K;
    Wt[idx] = f2b(W[(size_t)k * N + n]);
}

// ---------------- V [8192][512] -> Vt [32][64][2048] ----------------
__global__ void transpose_v_k(const ushort* __restrict__ V, ushort* __restrict__ Vt) {
    int idx = blockIdx.x * blockDim.x + threadIdx.x;
    if (idx >= 32 * 64 * 2048) return;
    int nn = idx & 2047;
    int d  = (idx >> 11) & 63;
    int bh = idx >> 17;
    int b = bh >> 3, h = bh & 7;
    Vt[idx] = V[((size_t)(b * 2048 + nn)) * 512 + h * 64 + d];
}

// ---------------- per-64-chunk l2 normalize (in place) ----------------
__global__ void l2norm_k(ushort* __restrict__ T, int nchunk) {
    int tid = blockIdx.x * blockDim.x + threadIdx.x;
    int chunk = tid >> 4;
    if (chunk >= nchunk) return;
    int part = tid & 15;
    ushort* p = T + (size_t)chunk * 64 + part * 4;
    ushort4 u = *reinterpret_cast<ushort4*>(p);
    float x0 = b2f(u.x), x1 = b2f(u.y), x2 = b2f(u.z), x3 = b2f(u.w);
    float ss = x0 * x0 + x1 * x1 + x2 * x2 + x3 * x3;
    ss += __shfl_xor(ss, 1);
    ss += __shfl_xor(ss, 2);
    ss += __shfl_xor(ss, 4);
    ss += __shfl_xor(ss, 8);
    float inv = 1.0f / fmaxf(sqrtf(ss), 1e-12f);
    u.x = f2b(x0 * inv); u.y = f2b(x1 * inv); u.z = f2b(x2 * inv); u.w = f2b(x3 * inv);
    *reinterpret_cast<ushort4*>(p) = u;
}

// ---------------- GEMM: C[M][N] = A[M][K](bf16) * Bt[N][K](bf16)^T ----------------
template <int F32OUT>
__global__ __launch_bounds__(256)
void gemm_bt_k(const ushort* __restrict__ A, const ushort* __restrict__ Bt,
               void* __restrict__ Cout, int M, int N, int K) {
    const int lane = threadIdx.x & 63;
    const int wave = threadIdx.x >> 6;
    const int l15 = lane & 15, g = lane >> 4;
    const int rbase = (blockIdx.x * 4 + wave) * 16;
    const int cbase = blockIdx.y * 64;
    const ushort* Ap = A + (size_t)(rbase + l15) * K + 8 * g;
    const ushort* Bp = Bt + (size_t)(cbase + l15) * K + 8 * g;
    f32x4 acc[4] = {{0,0,0,0},{0,0,0,0},{0,0,0,0},{0,0,0,0}};
    for (int k = 0; k < K; k += 32) {
        bf16x8 a = *reinterpret_cast<const bf16x8*>(Ap + k);
#pragma unroll
        for (int c = 0; c < 4; ++c) {
            bf16x8 bfr = *reinterpret_cast<const bf16x8*>(Bp + (size_t)(c * 16) * K + k);
            acc[c] = MFMA16(a, bfr, acc[c]);
        }
    }
#pragma unroll
    for (int c = 0; c < 4; ++c) {
#pragma unroll
        for (int r = 0; r < 4; ++r) {
            int row = rbase + 4 * g + r;
            int col = cbase + c * 16 + l15;
            if (F32OUT)
                reinterpret_cast<float*>(Cout)[(size_t)row * N + col] = acc[c][r];
            else
                reinterpret_cast<ushort*>(Cout)[(size_t)row * N + col] = f2b(acc[c][r]);
        }
    }
}

// ---------------- causal cosine-sim flash attention (v2) ----------------
// Fixed softmax offset 8 (S = 8*cos <= 8): no running max, no rescale.
// Each wave owns q-tiles c and 127-c (16 rows each) -> 33 kv-tile steps for
// every wave (perfect balance). KVBLK=64. K reg-double-buffered, V issued
// early each step. No LDS, no barriers.
__global__ __launch_bounds__(128, 2)
void flash_attn_k(const ushort* __restrict__ Q, const ushort* __restrict__ K,
                  const ushort* __restrict__ Vt, ushort* __restrict__ O) {
    const int lane = threadIdx.x & 63;
    const int wave = threadIdx.x >> 6;
    const int l15 = lane & 15;
    const int g = lane >> 4;
    const int bh = blockIdx.x;
    const int b = bh >> 3, h = bh & 7;
    const int wglob = blockIdx.y * 2 + wave;  // 0..63
    const int c0 = wglob;          // light q-tile
    const int c1 = 127 - wglob;    // heavy q-tile
    const int q0 = c0 * 16 + l15;
    const int q1 = c1 * 16 + l15;
    const int nt0 = (c0 * 16 + 79) >> 6;  // kv tiles for rt0 (last one masked)
    const int nt1 = (c1 * 16 + 79) >> 6;

    const ushort* Qb = Q + (size_t)(b * 2048) * 512 + h * 64;
    const ushort* Kb = K + (size_t)(b * 2048) * 512 + h * 64;
    const ushort* Vb = Vt + (size_t)bh * 64 * 2048;

    bf16x8 qf0[2], qf1[2];
#pragma unroll
    for (int kh = 0; kh < 2; ++kh) {
        qf0[kh] = *reinterpret_cast<const bf16x8*>(Qb + (size_t)q0 * 512 + 32 * kh + 8 * g);
        qf1[kh] = *reinterpret_cast<const bf16x8*>(Qb + (size_t)q1 * 512 + 32 * kh + 8 * g);
    }

    f32x4 acc0[4], acc1[4];
#pragma unroll
    for (int d = 0; d < 4; ++d) {
        acc0[d] = (f32x4){0, 0, 0, 0};
        acc1[d] = (f32x4){0, 0, 0, 0};
    }
    float ls0 = 0.0f, ls1 = 0.0f;

    bf16x8 kA[4][2], kB[4][2];

    auto loadK = [&](bf16x8 (&kb)[4][2], int t) {
        const ushort* base = Kb + (size_t)(t * 64 + l15) * 512 + 8 * g;
#pragma unroll
        for (int jt = 0; jt < 4; ++jt)
#pragma unroll
            for (int kh = 0; kh < 2; ++kh)
                kb[jt][kh] = *reinterpret_cast<const bf16x8*>(base + (size_t)jt * 16 * 512 + 32 * kh);
    };

    auto step = [&](bf16x8 (&kb)[4][2], int t) {
        // V loads issued early, consumed after S+softmax
        bf16x4 vf[4][2][2];
        const ushort* vb = Vb + (size_t)l15 * 2048 + t * 64 + 4 * g;
#pragma unroll
        for (int d = 0; d < 4; ++d)
#pragma unroll
            for (int kk = 0; kk < 2; ++kk)
#pragma unroll
                for (int th = 0; th < 2; ++th)
                    vf[d][kk][th] = *reinterpret_cast<const bf16x4*>(
                        vb + (size_t)d * 16 * 2048 + 32 * kk + 16 * th);

        const bool act0 = (t < nt0);
        const bool mk0 = (t == nt0 - 1);
        const bool mk1 = (t == nt1 - 1);

        // S^T = mfma(K, Q) for both row-tiles
        f32x4 s1[4];
#pragma unroll
        for (int jt = 0; jt < 4; ++jt) {
            f32x4 z = {0, 0, 0, 0};
            z = MFMA16(kb[jt][0], qf1[0], z);
            s1[jt] = MFMA16(kb[jt][1], qf1[1], z);
        }

        // softmax + pack rt1
        bf16x8 pt1[2];
        float la1 = 0.0f;
#pragma unroll
        for (int jt = 0; jt < 4; ++jt) {
#pragma unroll
            for (int r = 0; r < 4; ++r) {
                float p = __expf(fmaf(s1[jt][r], 8.0f, -8.0f));
                if (mk1) {
                    int j = t * 64 + jt * 16 + 4 * g + r;
                    p = (j <= q1) ? p : 0.0f;
                }
                la1 += p;
                pt1[jt >> 1][(jt & 1) * 4 + r] = (__bf16)p;
            }
        }
        ls1 += la1;

        // PV rt1
#pragma unroll
        for (int d = 0; d < 4; ++d) {
            bf16x8 v0 = cat44(vf[d][0][0], vf[d][0][1]);
            bf16x8 v1 = cat44(vf[d][1][0], vf[d][1][1]);
            acc1[d] = MFMA16(v0, pt1[0], acc1[d]);
            acc1[d] = MFMA16(v1, pt1[1], acc1[d]);
        }

        if (act0) {
            f32x4 s0[4];
#pragma unroll
            for (int jt = 0; jt < 4; ++jt) {
                f32x4 z = {0, 0, 0, 0};
                z = MFMA16(kb[jt][0], qf0[0], z);
                s0[jt] = MFMA16(kb[jt][1], qf0[1], z);
            }
            bf16x8 pt0[2];
            float la0 = 0.0f;
#pragma unroll
            for (int jt = 0; jt < 4; ++jt) {
#pragma unroll
                for (int r = 0; r < 4; ++r) {
                    float p = __expf(fmaf(s0[jt][r], 8.0f, -8.0f));
                    if (mk0) {
                        int j = t * 64 + jt * 16 + 4 * g + r;
                        p = (j <= q0) ? p : 0.0f;
                    }
                    la0 += p;
                    pt0[jt >> 1][(jt & 1) * 4 + r] = (__bf16)p;
                }
            }
            ls0 += la0;
#pragma unroll
            for (int d = 0; d < 4; ++d) {
                bf16x8 v0 = cat44(vf[d][0][0], vf[d][0][1]);
                bf16x8 v1 = cat44(vf[d][1][0], vf[d][1][1]);
                acc0[d] = MFMA16(v0, pt0[0], acc0[d]);
                acc0[d] = MFMA16(v1, pt0[1], acc0[d]);
            }
        }
    };

    // main loop: K double-buffered, unroll-2 with named buffers (static idx)
    loadK(kA, 0);
    int t = 0;
    for (;;) {
        if (t + 1 < nt1) loadK(kB, t + 1);
        step(kA, t);
        if (++t >= nt1) break;
        if (t + 1 < nt1) loadK(kA, t + 1);
        step(kB, t);
        if (++t >= nt1) break;
    }

    // epilogue: reduce lsum over g, normalize, store
    auto fin = [&](f32x4 (&acc)[4], float ls, int qr) {
        ls += __shfl_xor(ls, 16);
        ls += __shfl_xor(ls, 32);
        float inv = 1.0f / ls;
        ushort* Ob = O + (size_t)(b * 2048 + qr) * 512 + h * 64;
#pragma unroll
        for (int d = 0; d < 4; ++d) {
            bf16x4 w;
#pragma unroll
            for (int r = 0; r < 4; ++r) w[r] = (__bf16)(acc[d][r] * inv);
            *reinterpret_cast<bf16x4*>(Ob + d * 16 + 4 * g) = w;
        }
    };
    fin(acc1, ls1, q1);
    fin(acc0, ls0, q0);
}

extern "C" void kernel_launch(void* const* d_in, const int* in_sizes, int n_in,
                              void* d_out, int out_size, void* d_ws, size_t ws_size,
                              hipStream_t stream) {
    const float* x  = (const float*)d_in[0];
    const float* Wq = (const float*)d_in[1];
    const float* Wk = (const float*)d_in[2];
    const float* Wv = (const float*)d_in[3];
    const float* Wo = (const float*)d_in[4];
    float* out = (float*)d_out;

    char* ws = (char*)d_ws;
    ushort* xb  = (ushort*)ws; ws += (size_t)8192 * 1024 * 2;  // 16 MB
    ushort* Wqt = (ushort*)ws; ws += (size_t)512 * 1024 * 2;
    ushort* Wkt = (ushort*)ws; ws += (size_t)512 * 1024 * 2;
    ushort* Wvt = (ushort*)ws; ws += (size_t)512 * 1024 * 2;
    ushort* Wot = (ushort*)ws; ws += (size_t)1024 * 512 * 2;
    ushort* Qm  = (ushort*)ws; ws += (size_t)8192 * 512 * 2;
    ushort* Km  = (ushort*)ws; ws += (size_t)8192 * 512 * 2;
    ushort* Vm  = (ushort*)ws; ws += (size_t)8192 * 512 * 2;
    ushort* Vtm = (ushort*)ws; ws += (size_t)8192 * 512 * 2;
    ushort* Om  = xb;  // reuse: xb dead after QKV GEMMs

    f32_to_bf16_k<<<8192, 256, 0, stream>>>(x, xb, 2097152);
    transpose_w_k<<<2048, 256, 0, stream>>>(Wq, Wqt, 1024, 512);
    transpose_w_k<<<2048, 256, 0, stream>>>(Wk, Wkt, 1024, 512);
    transpose_w_k<<<2048, 256, 0, stream>>>(Wv, Wvt, 1024, 512);
    transpose_w_k<<<2048, 256, 0, stream>>>(Wo, Wot, 512, 1024);

    gemm_bt_k<0><<<dim3(128, 8), 256, 0, stream>>>(xb, Wqt, Qm, 8192, 512, 1024);
    gemm_bt_k<0><<<dim3(128, 8), 256, 0, stream>>>(xb, Wkt, Km, 8192, 512, 1024);
    gemm_bt_k<0><<<dim3(128, 8), 256, 0, stream>>>(xb, Wvt, Vm, 8192, 512, 1024);

    l2norm_k<<<4096, 256, 0, stream>>>(Qm, 65536);
    l2norm_k<<<4096, 256, 0, stream>>>(Km, 65536);

    transpose_v_k<<<16384, 256, 0, stream>>>(Vm, Vtm);

    flash_attn_k<<<dim3(32, 32), 128, 0, stream>>>(Qm, Km, Vtm, Om);

    gemm_bt_k<1><<<dim3(128, 16), 256, 0, stream>>>(Om, Wot, out, 8192, 1024, 512);
}

// Round 4
// 241.427 us; speedup vs baseline: 2.8095x; 2.0282x over previous
//
#include <hip/hip_runtime.h>
#include <hip/hip_bf16.h>

typedef __attribute__((ext_vector_type(8))) __bf16 bf16x8;
typedef __attribute__((ext_vector_type(4))) __bf16 bf16x4;
typedef __attribute__((ext_vector_type(4))) float f32x4;

#define MFMA16(a, b, c) __builtin_amdgcn_mfma_f32_16x16x32_bf16(a, b, c, 0, 0, 0)

static __device__ __forceinline__ ushort f2b(float f) {
    __bf16 b = (__bf16)f;
    return __builtin_bit_cast(ushort, b);
}
static __device__ __forceinline__ float b2f(ushort u) {
    __bf16 b = __builtin_bit_cast(__bf16, u);
    return (float)b;
}
static __device__ __forceinline__ bf16x8 cat44(bf16x4 a, bf16x4 b) {
    bf16x8 r;
    r[0] = a[0]; r[1] = a[1]; r[2] = a[2]; r[3] = a[3];
    r[4] = b[0]; r[5] = b[1]; r[6] = b[2]; r[7] = b[3];
    return r;
}
static __device__ __forceinline__ void gload_lds16(const ushort* g, ushort* l) {
    __builtin_amdgcn_global_load_lds(
        (const __attribute__((address_space(1))) unsigned int*)g,
        (__attribute__((address_space(3))) unsigned int*)l, 16, 0, 0);
}

// ---------------- f32 -> bf16 convert (vectorized) ----------------
__global__ void f32_to_bf16_k(const float* __restrict__ in, ushort* __restrict__ out, int n4) {
    int i = blockIdx.x * blockDim.x + threadIdx.x;
    if (i >= n4) return;
    float4 v = reinterpret_cast<const float4*>(in)[i];
    ushort4 o;
    o.x = f2b(v.x); o.y = f2b(v.y); o.z = f2b(v.z); o.w = f2b(v.w);
    reinterpret_cast<ushort4*>(out)[i] = o;
}

// ---------------- W [K][N] f32  ->  Wt [N][K] bf16 ----------------
__global__ void transpose_w_k(const float* __restrict__ W, ushort* __restrict__ Wt, int K, int N) {
    int idx = blockIdx.x * blockDim.x + threadIdx.x;
    if (idx >= K * N) return;
    int n = idx / K, k = idx - n * K;
    Wt[idx] = f2b(W[(size_t)k * N + n]);
}

// ---------------- V [8192][512] -> Vt [32][64][2048] ----------------
__global__ void transpose_v_k(const ushort* __restrict__ V, ushort* __restrict__ Vt) {
    int idx = blockIdx.x * blockDim.x + threadIdx.x;
    if (idx >= 32 * 64 * 2048) return;
    int nn = idx & 2047;
    int d  = (idx >> 11) & 63;
    int bh = idx >> 17;
    int b = bh >> 3, h = bh & 7;
    Vt[idx] = V[((size_t)(b * 2048 + nn)) * 512 + h * 64 + d];
}

// ---------------- per-64-chunk l2 normalize (in place) ----------------
__global__ void l2norm_k(ushort* __restrict__ T, int nchunk) {
    int tid = blockIdx.x * blockDim.x + threadIdx.x;
    int chunk = tid >> 4;
    if (chunk >= nchunk) return;
    int part = tid & 15;
    ushort* p = T + (size_t)chunk * 64 + part * 4;
    ushort4 u = *reinterpret_cast<ushort4*>(p);
    float x0 = b2f(u.x), x1 = b2f(u.y), x2 = b2f(u.z), x3 = b2f(u.w);
    float ss = x0 * x0 + x1 * x1 + x2 * x2 + x3 * x3;
    ss += __shfl_xor(ss, 1);
    ss += __shfl_xor(ss, 2);
    ss += __shfl_xor(ss, 4);
    ss += __shfl_xor(ss, 8);
    float inv = 1.0f / fmaxf(sqrtf(ss), 1e-12f);
    u.x = f2b(x0 * inv); u.y = f2b(x1 * inv); u.z = f2b(x2 * inv); u.w = f2b(x3 * inv);
    *reinterpret_cast<ushort4*>(p) = u;
}

// ---------------- tiled GEMM (m97 structure): C = A[M][K] * Bt[N][K]^T ----------------
// 128x128 tile, BK=32, 4 waves x (64x64), global_load_lds staging, 2 barriers/K-step.
// ROUTE=1: N=1536 QKV-fused output -> route cols to C0/C1/C2 with ldc=512 (bf16).
template <int F32OUT, int ROUTE>
__global__ __launch_bounds__(256)
void gemm_tile_k(const ushort* __restrict__ A, const ushort* __restrict__ Bt,
                 void* __restrict__ C0, void* __restrict__ C1, void* __restrict__ C2,
                 int M, int N, int K, int nby) {
    __shared__ __align__(16) ushort As[128 * 32];
    __shared__ __align__(16) ushort Bs[128 * 32];
    const int tid = threadIdx.x;
    const int lane = tid & 63;
    const int w = tid >> 6;
    const int l15 = lane & 15, g = lane >> 4;
    const int wr = w >> 1, wc = w & 1;

    // bijective XCD swizzle (requires gridDim.x % 8 == 0)
    const int nwg = gridDim.x;
    const int cpx = nwg >> 3;
    const int bid = blockIdx.x;
    const int swz = (bid & 7) * cpx + (bid >> 3);
    const int bx = swz / nby, by = swz - bx * nby;
    const int rbase = bx * 128, cbase = by * 128;

    // staging: wave w covers tile rows [32w, 32w+32): two 16-row chunks.
    // lane l -> row +(l>>2), k-elem offset (l&3)*8  (16B per lane, LDS-linear)
    const int srow = lane >> 2;
    const int scol = (lane & 3) * 8;
    const ushort* Aw0 = A + (size_t)(rbase + 32 * w + srow) * K + scol;
    const ushort* Bw0 = Bt + (size_t)(cbase + 32 * w + srow) * K + scol;

    f32x4 acc[4][4];
#pragma unroll
    for (int m = 0; m < 4; ++m)
#pragma unroll
        for (int n = 0; n < 4; ++n) acc[m][n] = (f32x4){0, 0, 0, 0};

    const int nk = K >> 5;
    for (int kt = 0; kt < nk; ++kt) {
        const int k0 = kt << 5;
        if (kt) __syncthreads();
        gload_lds16(Aw0 + k0,          &As[(32 * w) * 32]);
        gload_lds16(Aw0 + 16 * K + k0, &As[(32 * w + 16) * 32]);
        gload_lds16(Bw0 + k0,          &Bs[(32 * w) * 32]);
        gload_lds16(Bw0 + 16 * K + k0, &Bs[(32 * w + 16) * 32]);
        __syncthreads();
        bf16x8 af[4], bf[4];
#pragma unroll
        for (int m = 0; m < 4; ++m)
            af[m] = *reinterpret_cast<const bf16x8*>(&As[(64 * wr + 16 * m + l15) * 32 + 8 * g]);
#pragma unroll
        for (int n = 0; n < 4; ++n)
            bf[n] = *reinterpret_cast<const bf16x8*>(&Bs[(64 * wc + 16 * n + l15) * 32 + 8 * g]);
#pragma unroll
        for (int m = 0; m < 4; ++m)
#pragma unroll
            for (int n = 0; n < 4; ++n)
                acc[m][n] = MFMA16(af[m], bf[n], acc[m][n]);
    }

#pragma unroll
    for (int m = 0; m < 4; ++m)
#pragma unroll
        for (int n = 0; n < 4; ++n) {
            const int row = rbase + 64 * wr + 16 * m + 4 * g;
            const int col = cbase + 64 * wc + 16 * n + l15;
            if (ROUTE) {
                const int grp = col >> 9;
                const int co = col & 511;
                ushort* Cg = (ushort*)(grp == 0 ? C0 : (grp == 1 ? C1 : C2));
#pragma unroll
                for (int r = 0; r < 4; ++r)
                    Cg[(size_t)(row + r) * 512 + co] = f2b(acc[m][n][r]);
            } else if (F32OUT) {
#pragma unroll
                for (int r = 0; r < 4; ++r)
                    reinterpret_cast<float*>(C0)[(size_t)(row + r) * N + col] = acc[m][n][r];
            } else {
#pragma unroll
                for (int r = 0; r < 4; ++r)
                    reinterpret_cast<ushort*>(C0)[(size_t)(row + r) * N + col] = f2b(acc[m][n][r]);
            }
        }
}

// ---------------- causal cosine-sim flash attention (v2) ----------------
__global__ __launch_bounds__(128, 2)
void flash_attn_k(const ushort* __restrict__ Q, const ushort* __restrict__ K,
                  const ushort* __restrict__ Vt, ushort* __restrict__ O) {
    const int lane = threadIdx.x & 63;
    const int wave = threadIdx.x >> 6;
    const int l15 = lane & 15;
    const int g = lane >> 4;
    const int bh = blockIdx.x;
    const int b = bh >> 3, h = bh & 7;
    const int wglob = blockIdx.y * 2 + wave;  // 0..63
    const int c0 = wglob;
    const int c1 = 127 - wglob;
    const int q0 = c0 * 16 + l15;
    const int q1 = c1 * 16 + l15;
    const int nt0 = (c0 * 16 + 79) >> 6;
    const int nt1 = (c1 * 16 + 79) >> 6;

    const ushort* Qb = Q + (size_t)(b * 2048) * 512 + h * 64;
    const ushort* Kb = K + (size_t)(b * 2048) * 512 + h * 64;
    const ushort* Vb = Vt + (size_t)bh * 64 * 2048;

    bf16x8 qf0[2], qf1[2];
#pragma unroll
    for (int kh = 0; kh < 2; ++kh) {
        qf0[kh] = *reinterpret_cast<const bf16x8*>(Qb + (size_t)q0 * 512 + 32 * kh + 8 * g);
        qf1[kh] = *reinterpret_cast<const bf16x8*>(Qb + (size_t)q1 * 512 + 32 * kh + 8 * g);
    }

    f32x4 acc0[4], acc1[4];
#pragma unroll
    for (int d = 0; d < 4; ++d) {
        acc0[d] = (f32x4){0, 0, 0, 0};
        acc1[d] = (f32x4){0, 0, 0, 0};
    }
    float ls0 = 0.0f, ls1 = 0.0f;

    bf16x8 kA[4][2], kB[4][2];

    auto loadK = [&](bf16x8 (&kb)[4][2], int t) {
        const ushort* base = Kb + (size_t)(t * 64 + l15) * 512 + 8 * g;
#pragma unroll
        for (int jt = 0; jt < 4; ++jt)
#pragma unroll
            for (int kh = 0; kh < 2; ++kh)
                kb[jt][kh] = *reinterpret_cast<const bf16x8*>(base + (size_t)jt * 16 * 512 + 32 * kh);
    };

    auto step = [&](bf16x8 (&kb)[4][2], int t) {
        bf16x4 vf[4][2][2];
        const ushort* vb = Vb + (size_t)l15 * 2048 + t * 64 + 4 * g;
#pragma unroll
        for (int d = 0; d < 4; ++d)
#pragma unroll
            for (int kk = 0; kk < 2; ++kk)
#pragma unroll
                for (int th = 0; th < 2; ++th)
                    vf[d][kk][th] = *reinterpret_cast<const bf16x4*>(
                        vb + (size_t)d * 16 * 2048 + 32 * kk + 16 * th);

        const bool act0 = (t < nt0);
        const bool mk0 = (t == nt0 - 1);
        const bool mk1 = (t == nt1 - 1);

        f32x4 s1[4];
#pragma unroll
        for (int jt = 0; jt < 4; ++jt) {
            f32x4 z = {0, 0, 0, 0};
            z = MFMA16(kb[jt][0], qf1[0], z);
            s1[jt] = MFMA16(kb[jt][1], qf1[1], z);
        }

        bf16x8 pt1[2];
        float la1 = 0.0f;
#pragma unroll
        for (int jt = 0; jt < 4; ++jt) {
#pragma unroll
            for (int r = 0; r < 4; ++r) {
                float p = __expf(fmaf(s1[jt][r], 8.0f, -8.0f));
                if (mk1) {
                    int j = t * 64 + jt * 16 + 4 * g + r;
                    p = (j <= q1) ? p : 0.0f;
                }
                la1 += p;
                pt1[jt >> 1][(jt & 1) * 4 + r] = (__bf16)p;
            }
        }
        ls1 += la1;

#pragma unroll
        for (int d = 0; d < 4; ++d) {
            bf16x8 v0 = cat44(vf[d][0][0], vf[d][0][1]);
            bf16x8 v1 = cat44(vf[d][1][0], vf[d][1][1]);
            acc1[d] = MFMA16(v0, pt1[0], acc1[d]);
            acc1[d] = MFMA16(v1, pt1[1], acc1[d]);
        }

        if (act0) {
            f32x4 s0[4];
#pragma unroll
            for (int jt = 0; jt < 4; ++jt) {
                f32x4 z = {0, 0, 0, 0};
                z = MFMA16(kb[jt][0], qf0[0], z);
                s0[jt] = MFMA16(kb[jt][1], qf0[1], z);
            }
            bf16x8 pt0[2];
            float la0 = 0.0f;
#pragma unroll
            for (int jt = 0; jt < 4; ++jt) {
#pragma unroll
                for (int r = 0; r < 4; ++r) {
                    float p = __expf(fmaf(s0[jt][r], 8.0f, -8.0f));
                    if (mk0) {
                        int j = t * 64 + jt * 16 + 4 * g + r;
                        p = (j <= q0) ? p : 0.0f;
                    }
                    la0 += p;
                    pt0[jt >> 1][(jt & 1) * 4 + r] = (__bf16)p;
                }
            }
            ls0 += la0;
#pragma unroll
            for (int d = 0; d < 4; ++d) {
                bf16x8 v0 = cat44(vf[d][0][0], vf[d][0][1]);
                bf16x8 v1 = cat44(vf[d][1][0], vf[d][1][1]);
                acc0[d] = MFMA16(v0, pt0[0], acc0[d]);
                acc0[d] = MFMA16(v1, pt0[1], acc0[d]);
            }
        }
    };

    loadK(kA, 0);
    int t = 0;
    for (;;) {
        if (t + 1 < nt1) loadK(kB, t + 1);
        step(kA, t);
        if (++t >= nt1) break;
        if (t + 1 < nt1) loadK(kA, t + 1);
        step(kB, t);
        if (++t >= nt1) break;
    }

    auto fin = [&](f32x4 (&acc)[4], float ls, int qr) {
        ls += __shfl_xor(ls, 16);
        ls += __shfl_xor(ls, 32);
        float inv = 1.0f / ls;
        ushort* Ob = O + (size_t)(b * 2048 + qr) * 512 + h * 64;
#pragma unroll
        for (int d = 0; d < 4; ++d) {
            bf16x4 w;
#pragma unroll
            for (int r = 0; r < 4; ++r) w[r] = (__bf16)(acc[d][r] * inv);
            *reinterpret_cast<bf16x4*>(Ob + d * 16 + 4 * g) = w;
        }
    };
    fin(acc1, ls1, q1);
    fin(acc0, ls0, q0);
}

extern "C" void kernel_launch(void* const* d_in, const int* in_sizes, int n_in,
                              void* d_out, int out_size, void* d_ws, size_t ws_size,
                              hipStream_t stream) {
    const float* x  = (const float*)d_in[0];
    const float* Wq = (const float*)d_in[1];
    const float* Wk = (const float*)d_in[2];
    const float* Wv = (const float*)d_in[3];
    const float* Wo = (const float*)d_in[4];
    float* out = (float*)d_out;

    char* ws = (char*)d_ws;
    ushort* xb  = (ushort*)ws; ws += (size_t)8192 * 1024 * 2;  // 16 MB
    ushort* Wqt = (ushort*)ws; ws += (size_t)512 * 1024 * 2;   // contiguous:
    ushort* Wkt = (ushort*)ws; ws += (size_t)512 * 1024 * 2;   //  [1536][1024]
    ushort* Wvt = (ushort*)ws; ws += (size_t)512 * 1024 * 2;   //  fused B
    ushort* Wot = (ushort*)ws; ws += (size_t)1024 * 512 * 2;
    ushort* Qm  = (ushort*)ws; ws += (size_t)8192 * 512 * 2;
    ushort* Km  = (ushort*)ws; ws += (size_t)8192 * 512 * 2;
    ushort* Vm  = (ushort*)ws; ws += (size_t)8192 * 512 * 2;
    ushort* Vtm = (ushort*)ws; ws += (size_t)8192 * 512 * 2;
    ushort* Om  = xb;  // reuse: xb dead after QKV GEMM

    f32_to_bf16_k<<<8192, 256, 0, stream>>>(x, xb, 2097152);
    transpose_w_k<<<2048, 256, 0, stream>>>(Wq, Wqt, 1024, 512);
    transpose_w_k<<<2048, 256, 0, stream>>>(Wk, Wkt, 1024, 512);
    transpose_w_k<<<2048, 256, 0, stream>>>(Wv, Wvt, 1024, 512);
    transpose_w_k<<<2048, 256, 0, stream>>>(Wo, Wot, 512, 1024);

    // fused QKV GEMM: [8192][1024] x [1536][1024]^T -> Qm|Km|Vm
    gemm_tile_k<0, 1><<<768, 256, 0, stream>>>(xb, Wqt, Qm, Km, Vm, 8192, 1536, 1024, 12);

    l2norm_k<<<4096, 256, 0, stream>>>(Qm, 65536);
    l2norm_k<<<4096, 256, 0, stream>>>(Km, 65536);

    transpose_v_k<<<16384, 256, 0, stream>>>(Vm, Vtm);

    flash_attn_k<<<dim3(32, 32), 128, 0, stream>>>(Qm, Km, Vtm, Om);

    // out projection: [8192][512] x [1024][512]^T -> out (f32)
    gemm_tile_k<1, 0><<<512, 256, 0, stream>>>(Om, Wot, out, nullptr, nullptr, 8192, 1024, 512, 8);
}

// Round 5
// 143.821 us; speedup vs baseline: 4.7162x; 1.6787x over previous
//
#include <hip/hip_runtime.h>
#include <hip/hip_bf16.h>

typedef __attribute__((ext_vector_type(8))) __bf16 bf16x8;
typedef __attribute__((ext_vector_type(4))) __bf16 bf16x4;
typedef __attribute__((ext_vector_type(4))) float f32x4;

#define MFMA16(a, b, c) __builtin_amdgcn_mfma_f32_16x16x32_bf16(a, b, c, 0, 0, 0)

static __device__ __forceinline__ ushort f2b(float f) {
    __bf16 b = (__bf16)f;
    return __builtin_bit_cast(ushort, b);
}
static __device__ __forceinline__ float b2f(ushort u) {
    __bf16 b = __builtin_bit_cast(__bf16, u);
    return (float)b;
}
static __device__ __forceinline__ bf16x8 cat44(bf16x4 a, bf16x4 b) {
    bf16x8 r;
    r[0] = a[0]; r[1] = a[1]; r[2] = a[2]; r[3] = a[3];
    r[4] = b[0]; r[5] = b[1]; r[6] = b[2]; r[7] = b[3];
    return r;
}
static __device__ __forceinline__ void gload_lds16(const ushort* g, ushort* l) {
    __builtin_amdgcn_global_load_lds(
        (const __attribute__((address_space(1))) unsigned int*)g,
        (__attribute__((address_space(3))) unsigned int*)l, 16, 0, 0);
}

// ---------------- f32 -> bf16 convert (vectorized) ----------------
__global__ void f32_to_bf16_k(const float* __restrict__ in, ushort* __restrict__ out, int n4) {
    int i = blockIdx.x * blockDim.x + threadIdx.x;
    if (i >= n4) return;
    float4 v = reinterpret_cast<const float4*>(in)[i];
    ushort4 o;
    o.x = f2b(v.x); o.y = f2b(v.y); o.z = f2b(v.z); o.w = f2b(v.w);
    reinterpret_cast<ushort4*>(out)[i] = o;
}

// ---------------- W [K][N] f32  ->  Wt [N][K] bf16 ----------------
__global__ void transpose_w_k(const float* __restrict__ W, ushort* __restrict__ Wt, int K, int N) {
    int idx = blockIdx.x * blockDim.x + threadIdx.x;
    if (idx >= K * N) return;
    int n = idx / K, k = idx - n * K;
    Wt[idx] = f2b(W[(size_t)k * N + n]);
}

// ---------------- V [8192][512] -> Vt [32][64][2048] ----------------
__global__ void transpose_v_k(const ushort* __restrict__ V, ushort* __restrict__ Vt) {
    int idx = blockIdx.x * blockDim.x + threadIdx.x;
    if (idx >= 32 * 64 * 2048) return;
    int nn = idx & 2047;
    int d  = (idx >> 11) & 63;
    int bh = idx >> 17;
    int b = bh >> 3, h = bh & 7;
    Vt[idx] = V[((size_t)(b * 2048 + nn)) * 512 + h * 64 + d];
}

// ---------------- per-64-chunk l2 normalize (in place) ----------------
__global__ void l2norm_k(ushort* __restrict__ T, int nchunk) {
    int tid = blockIdx.x * blockDim.x + threadIdx.x;
    int chunk = tid >> 4;
    if (chunk >= nchunk) return;
    int part = tid & 15;
    ushort* p = T + (size_t)chunk * 64 + part * 4;
    ushort4 u = *reinterpret_cast<ushort4*>(p);
    float x0 = b2f(u.x), x1 = b2f(u.y), x2 = b2f(u.z), x3 = b2f(u.w);
    float ss = x0 * x0 + x1 * x1 + x2 * x2 + x3 * x3;
    ss += __shfl_xor(ss, 1);
    ss += __shfl_xor(ss, 2);
    ss += __shfl_xor(ss, 4);
    ss += __shfl_xor(ss, 8);
    float inv = 1.0f / fmaxf(sqrtf(ss), 1e-12f);
    u.x = f2b(x0 * inv); u.y = f2b(x1 * inv); u.z = f2b(x2 * inv); u.w = f2b(x3 * inv);
    *reinterpret_cast<ushort4*>(p) = u;
}

// ---------------- tiled GEMM (m97 structure): C = A[M][K] * Bt[N][K]^T ----------------
template <int F32OUT, int ROUTE>
__global__ __launch_bounds__(256)
void gemm_tile_k(const ushort* __restrict__ A, const ushort* __restrict__ Bt,
                 void* __restrict__ C0, void* __restrict__ C1, void* __restrict__ C2,
                 int M, int N, int K, int nby) {
    __shared__ __align__(16) ushort As[128 * 32];
    __shared__ __align__(16) ushort Bs[128 * 32];
    const int tid = threadIdx.x;
    const int lane = tid & 63;
    const int w = tid >> 6;
    const int l15 = lane & 15, g = lane >> 4;
    const int wr = w >> 1, wc = w & 1;

    const int nwg = gridDim.x;
    const int cpx = nwg >> 3;
    const int bid = blockIdx.x;
    const int swz = (bid & 7) * cpx + (bid >> 3);
    const int bx = swz / nby, by = swz - bx * nby;
    const int rbase = bx * 128, cbase = by * 128;

    const int srow = lane >> 2;
    const int scol = (lane & 3) * 8;
    const ushort* Aw0 = A + (size_t)(rbase + 32 * w + srow) * K + scol;
    const ushort* Bw0 = Bt + (size_t)(cbase + 32 * w + srow) * K + scol;

    f32x4 acc[4][4];
#pragma unroll
    for (int m = 0; m < 4; ++m)
#pragma unroll
        for (int n = 0; n < 4; ++n) acc[m][n] = (f32x4){0, 0, 0, 0};

    const int nk = K >> 5;
    for (int kt = 0; kt < nk; ++kt) {
        const int k0 = kt << 5;
        if (kt) __syncthreads();
        gload_lds16(Aw0 + k0,          &As[(32 * w) * 32]);
        gload_lds16(Aw0 + 16 * K + k0, &As[(32 * w + 16) * 32]);
        gload_lds16(Bw0 + k0,          &Bs[(32 * w) * 32]);
        gload_lds16(Bw0 + 16 * K + k0, &Bs[(32 * w + 16) * 32]);
        __syncthreads();
        bf16x8 af[4], bf[4];
#pragma unroll
        for (int m = 0; m < 4; ++m)
            af[m] = *reinterpret_cast<const bf16x8*>(&As[(64 * wr + 16 * m + l15) * 32 + 8 * g]);
#pragma unroll
        for (int n = 0; n < 4; ++n)
            bf[n] = *reinterpret_cast<const bf16x8*>(&Bs[(64 * wc + 16 * n + l15) * 32 + 8 * g]);
#pragma unroll
        for (int m = 0; m < 4; ++m)
#pragma unroll
            for (int n = 0; n < 4; ++n)
                acc[m][n] = MFMA16(af[m], bf[n], acc[m][n]);
    }

#pragma unroll
    for (int m = 0; m < 4; ++m)
#pragma unroll
        for (int n = 0; n < 4; ++n) {
            const int row = rbase + 64 * wr + 16 * m + 4 * g;
            const int col = cbase + 64 * wc + 16 * n + l15;
            if (ROUTE) {
                const int grp = col >> 9;
                const int co = col & 511;
                ushort* Cg = (ushort*)(grp == 0 ? C0 : (grp == 1 ? C1 : C2));
#pragma unroll
                for (int r = 0; r < 4; ++r)
                    Cg[(size_t)(row + r) * 512 + co] = f2b(acc[m][n][r]);
            } else if (F32OUT) {
#pragma unroll
                for (int r = 0; r < 4; ++r)
                    reinterpret_cast<float*>(C0)[(size_t)(row + r) * N + col] = acc[m][n][r];
            } else {
#pragma unroll
                for (int r = 0; r < 4; ++r)
                    reinterpret_cast<ushort*>(C0)[(size_t)(row + r) * N + col] = f2b(acc[m][n][r]);
            }
        }
}

// ---------------- causal cosine-sim flash attention (v3: LDS-cooperative) ----------------
// 4 waves/block share K/V 64x64 tiles in LDS (global_load_lds, 16B-granule XOR
// swizzle chunk^=(row&7) on both stage-source and read side). Tile-pairing
// (c, 127-c) per wave; fixed softmax offset 8 (S<=8); m97 2-barrier step.
__global__ __launch_bounds__(256, 2)
void flash_attn_k(const ushort* __restrict__ Q, const ushort* __restrict__ K,
                  const ushort* __restrict__ Vt, ushort* __restrict__ O) {
    __shared__ __align__(16) ushort Ks[64 * 64];
    __shared__ __align__(16) ushort Vs[64 * 64];
    const int tid = threadIdx.x;
    const int lane = tid & 63;
    const int wave = tid >> 6;
    const int l15 = lane & 15;
    const int g = lane >> 4;
    const int bh = blockIdx.x;
    const int b = bh >> 3, h = bh & 7;
    const int wglob = blockIdx.y * 4 + wave;  // 0..63
    const int c0 = wglob;
    const int c1 = 127 - wglob;
    const int q0 = c0 * 16 + l15;
    const int q1 = c1 * 16 + l15;
    const int nt0 = (c0 * 16 + 79) >> 6;
    const int nt1 = (c1 * 16 + 79) >> 6;
    const int ntb = ((127 - blockIdx.y * 4) * 16 + 79) >> 6;  // block max (wave 0)

    const ushort* Qb = Q + (size_t)(b * 2048) * 512 + h * 64;
    const ushort* Kb = K + (size_t)(b * 2048) * 512 + h * 64;
    const ushort* Vb = Vt + (size_t)bh * 64 * 2048;

    // staging: thread stages 16B slots tid and tid+256 of each 8KB tile.
    // slot s -> row=s>>3, chunk c=s&7; source chunk = c ^ (row&7)  (inverse swz)
    const int r1 = tid >> 3, cc = tid & 7;
    const int r2 = r1 + 32;
    const ushort* kS1 = Kb + (size_t)r1 * 512 + ((cc ^ (r1 & 7)) * 8);
    const ushort* kS2 = Kb + (size_t)r2 * 512 + ((cc ^ (r2 & 7)) * 8);
    const ushort* vS1 = Vb + (size_t)r1 * 2048 + ((cc ^ (r1 & 7)) * 8);
    const ushort* vS2 = Vb + (size_t)r2 * 2048 + ((cc ^ (r2 & 7)) * 8);
    ushort* kD1 = &Ks[wave * 512];
    ushort* kD2 = &Ks[2048 + wave * 512];
    ushort* vD1 = &Vs[wave * 512];
    ushort* vD2 = &Vs[2048 + wave * 512];

    bf16x8 qf0[2], qf1[2];
#pragma unroll
    for (int kh = 0; kh < 2; ++kh) {
        qf0[kh] = *reinterpret_cast<const bf16x8*>(Qb + (size_t)q0 * 512 + 32 * kh + 8 * g);
        qf1[kh] = *reinterpret_cast<const bf16x8*>(Qb + (size_t)q1 * 512 + 32 * kh + 8 * g);
    }

    f32x4 acc0[4], acc1[4];
#pragma unroll
    for (int d = 0; d < 4; ++d) {
        acc0[d] = (f32x4){0, 0, 0, 0};
        acc1[d] = (f32x4){0, 0, 0, 0};
    }
    float ls0 = 0.0f, ls1 = 0.0f;

    for (int t = 0; t < ntb; ++t) {
        if (t) __syncthreads();
        gload_lds16(kS1 + (size_t)t * 64 * 512, kD1);
        gload_lds16(kS2 + (size_t)t * 64 * 512, kD2);
        gload_lds16(vS1 + t * 64, vD1);
        gload_lds16(vS2 + t * 64, vD2);
        __syncthreads();

        if (t >= nt1) continue;  // wave done (still hits barriers next iter)
        const bool act0 = (t < nt0);
        const bool mk0 = (t == nt0 - 1);
        const bool mk1 = (t == nt1 - 1);

        // K fragments: A-operand row j = jt*16+l15, k(d) = 8g+32kh..: swizzled b128
        bf16x8 af[4][2];
#pragma unroll
        for (int jt = 0; jt < 4; ++jt)
#pragma unroll
            for (int kh = 0; kh < 2; ++kh) {
                const int row = jt * 16 + l15;
                const int chunk = (g + 4 * kh) ^ (row & 7);
                af[jt][kh] = *reinterpret_cast<const bf16x8*>(&Ks[row * 64 + chunk * 8]);
            }
        // V fragments: d-row = 16*dblk + l15, 8B half at swizzled chunk
        bf16x4 vf[4][2][2];
#pragma unroll
        for (int d = 0; d < 4; ++d)
#pragma unroll
            for (int kk = 0; kk < 2; ++kk)
#pragma unroll
                for (int th = 0; th < 2; ++th) {
                    const int dr = d * 16 + l15;
                    const int chunk = ((g >> 1) + 2 * th + 4 * kk) ^ (dr & 7);
                    vf[d][kk][th] = *reinterpret_cast<const bf16x4*>(
                        &Vs[dr * 64 + chunk * 8 + (g & 1) * 4]);
                }

        f32x4 s1[4];
#pragma unroll
        for (int jt = 0; jt < 4; ++jt) {
            f32x4 z = {0, 0, 0, 0};
            z = MFMA16(af[jt][0], qf1[0], z);
            s1[jt] = MFMA16(af[jt][1], qf1[1], z);
        }

        bf16x8 pt1[2];
        float la1 = 0.0f;
#pragma unroll
        for (int jt = 0; jt < 4; ++jt) {
#pragma unroll
            for (int r = 0; r < 4; ++r) {
                float p = __expf(fmaf(s1[jt][r], 8.0f, -8.0f));
                if (mk1) {
                    int j = t * 64 + jt * 16 + 4 * g + r;
                    p = (j <= q1) ? p : 0.0f;
                }
                la1 += p;
                pt1[jt >> 1][(jt & 1) * 4 + r] = (__bf16)p;
            }
        }
        ls1 += la1;

#pragma unroll
        for (int d = 0; d < 4; ++d) {
            bf16x8 v0 = cat44(vf[d][0][0], vf[d][0][1]);
            bf16x8 v1 = cat44(vf[d][1][0], vf[d][1][1]);
            acc1[d] = MFMA16(v0, pt1[0], acc1[d]);
            acc1[d] = MFMA16(v1, pt1[1], acc1[d]);
        }

        if (act0) {
            f32x4 s0[4];
#pragma unroll
            for (int jt = 0; jt < 4; ++jt) {
                f32x4 z = {0, 0, 0, 0};
                z = MFMA16(af[jt][0], qf0[0], z);
                s0[jt] = MFMA16(af[jt][1], qf0[1], z);
            }
            bf16x8 pt0[2];
            float la0 = 0.0f;
#pragma unroll
            for (int jt = 0; jt < 4; ++jt) {
#pragma unroll
                for (int r = 0; r < 4; ++r) {
                    float p = __expf(fmaf(s0[jt][r], 8.0f, -8.0f));
                    if (mk0) {
                        int j = t * 64 + jt * 16 + 4 * g + r;
                        p = (j <= q0) ? p : 0.0f;
                    }
                    la0 += p;
                    pt0[jt >> 1][(jt & 1) * 4 + r] = (__bf16)p;
                }
            }
            ls0 += la0;
#pragma unroll
            for (int d = 0; d < 4; ++d) {
                bf16x8 v0 = cat44(vf[d][0][0], vf[d][0][1]);
                bf16x8 v1 = cat44(vf[d][1][0], vf[d][1][1]);
                acc0[d] = MFMA16(v0, pt0[0], acc0[d]);
                acc0[d] = MFMA16(v1, pt0[1], acc0[d]);
            }
        }
    }

    auto fin = [&](f32x4 (&acc)[4], float ls, int qr) {
        ls += __shfl_xor(ls, 16);
        ls += __shfl_xor(ls, 32);
        float inv = 1.0f / ls;
        ushort* Ob = O + (size_t)(b * 2048 + qr) * 512 + h * 64;
#pragma unroll
        for (int d = 0; d < 4; ++d) {
            bf16x4 w;
#pragma unroll
            for (int r = 0; r < 4; ++r) w[r] = (__bf16)(acc[d][r] * inv);
            *reinterpret_cast<bf16x4*>(Ob + d * 16 + 4 * g) = w;
        }
    };
    fin(acc1, ls1, q1);
    fin(acc0, ls0, q0);
}

extern "C" void kernel_launch(void* const* d_in, const int* in_sizes, int n_in,
                              void* d_out, int out_size, void* d_ws, size_t ws_size,
                              hipStream_t stream) {
    const float* x  = (const float*)d_in[0];
    const float* Wq = (const float*)d_in[1];
    const float* Wk = (const float*)d_in[2];
    const float* Wv = (const float*)d_in[3];
    const float* Wo = (const float*)d_in[4];
    float* out = (float*)d_out;

    char* ws = (char*)d_ws;
    ushort* xb  = (ushort*)ws; ws += (size_t)8192 * 1024 * 2;  // 16 MB
    ushort* Wqt = (ushort*)ws; ws += (size_t)512 * 1024 * 2;   // contiguous:
    ushort* Wkt = (ushort*)ws; ws += (size_t)512 * 1024 * 2;   //  [1536][1024]
    ushort* Wvt = (ushort*)ws; ws += (size_t)512 * 1024 * 2;   //  fused B
    ushort* Wot = (ushort*)ws; ws += (size_t)1024 * 512 * 2;
    ushort* Qm  = (ushort*)ws; ws += (size_t)8192 * 512 * 2;
    ushort* Km  = (ushort*)ws; ws += (size_t)8192 * 512 * 2;
    ushort* Vm  = (ushort*)ws; ws += (size_t)8192 * 512 * 2;
    ushort* Vtm = (ushort*)ws; ws += (size_t)8192 * 512 * 2;
    ushort* Om  = xb;  // reuse: xb dead after QKV GEMM

    f32_to_bf16_k<<<8192, 256, 0, stream>>>(x, xb, 2097152);
    transpose_w_k<<<2048, 256, 0, stream>>>(Wq, Wqt, 1024, 512);
    transpose_w_k<<<2048, 256, 0, stream>>>(Wk, Wkt, 1024, 512);
    transpose_w_k<<<2048, 256, 0, stream>>>(Wv, Wvt, 1024, 512);
    transpose_w_k<<<2048, 256, 0, stream>>>(Wo, Wot, 512, 1024);

    // fused QKV GEMM: [8192][1024] x [1536][1024]^T -> Qm|Km|Vm
    gemm_tile_k<0, 1><<<768, 256, 0, stream>>>(xb, Wqt, Qm, Km, Vm, 8192, 1536, 1024, 12);

    l2norm_k<<<4096, 256, 0, stream>>>(Qm, 65536);
    l2norm_k<<<4096, 256, 0, stream>>>(Km, 65536);

    transpose_v_k<<<16384, 256, 0, stream>>>(Vm, Vtm);

    flash_attn_k<<<dim3(32, 16), 256, 0, stream>>>(Qm, Km, Vtm, Om);

    // out projection: [8192][512] x [1024][512]^T -> out (f32)
    gemm_tile_k<1, 0><<<512, 256, 0, stream>>>(Om, Wot, out, nullptr, nullptr, 8192, 1024, 512, 8);
}

// Round 6
// 108.257 us; speedup vs baseline: 6.2656x; 1.3285x over previous
//
#include <hip/hip_runtime.h>
#include <hip/hip_bf16.h>

typedef __attribute__((ext_vector_type(8))) __bf16 bf16x8;
typedef __attribute__((ext_vector_type(4))) __bf16 bf16x4;
typedef __attribute__((ext_vector_type(4))) float f32x4;

#define MFMA16(a, b, c) __builtin_amdgcn_mfma_f32_16x16x32_bf16(a, b, c, 0, 0, 0)

static __device__ __forceinline__ ushort f2b(float f) {
    __bf16 b = (__bf16)f;
    return __builtin_bit_cast(ushort, b);
}
static __device__ __forceinline__ bf16x8 cat44(bf16x4 a, bf16x4 b) {
    bf16x8 r;
    r[0] = a[0]; r[1] = a[1]; r[2] = a[2]; r[3] = a[3];
    r[4] = b[0]; r[5] = b[1]; r[6] = b[2]; r[7] = b[3];
    return r;
}
static __device__ __forceinline__ void gload_lds16(const ushort* g, ushort* l) {
    __builtin_amdgcn_global_load_lds(
        (const __attribute__((address_space(1))) unsigned int*)g,
        (__attribute__((address_space(3))) unsigned int*)l, 16, 0, 0);
}

// ---------------- f32 -> bf16 convert (vectorized) ----------------
__global__ void f32_to_bf16_k(const float* __restrict__ in, ushort* __restrict__ out, int n4) {
    int i = blockIdx.x * blockDim.x + threadIdx.x;
    if (i >= n4) return;
    float4 v = reinterpret_cast<const float4*>(in)[i];
    ushort4 o;
    o.x = f2b(v.x); o.y = f2b(v.y); o.z = f2b(v.z); o.w = f2b(v.w);
    reinterpret_cast<ushort4*>(out)[i] = o;
}

// ---------------- all W transposes, LDS-tiled, one launch ----------------
// dst[n][k] = bf16(src[k][n]); jobs 0-2: 1024x512 (Wq,Wk,Wv -> Wqkv rows), job 3: 512x1024 (Wo)
__global__ __launch_bounds__(256)
void transpose_all_k(const float* __restrict__ Wq, const float* __restrict__ Wk,
                     const float* __restrict__ Wv, const float* __restrict__ Wo,
                     ushort* __restrict__ Wqkv, ushort* __restrict__ Wot) {
    __shared__ ushort T[64][72];
    const int bid = blockIdx.x;
    const int job = bid >> 7;
    const int t = bid & 127;
    const float* src; ushort* dst; int K, N;
    if (job == 0)      { src = Wq; dst = Wqkv;                      K = 1024; N = 512; }
    else if (job == 1) { src = Wk; dst = Wqkv + (size_t)512 * 1024; K = 1024; N = 512; }
    else if (job == 2) { src = Wv; dst = Wqkv + (size_t)1024 * 1024; K = 1024; N = 512; }
    else               { src = Wo; dst = Wot;                       K = 512;  N = 1024; }
    const int tn = N >> 6;
    const int bk = t / tn, bn = t - bk * tn;
    const int k0 = bk * 64, n0 = bn * 64;
    const int tid = threadIdx.x;
#pragma unroll
    for (int q = 0; q < 4; ++q) {
        const int lin = tid + 256 * q;
        const int kr = lin >> 4;
        const int n4 = (lin & 15) << 2;
        float4 v = *reinterpret_cast<const float4*>(&src[(size_t)(k0 + kr) * N + n0 + n4]);
        T[n4 + 0][kr] = f2b(v.x);
        T[n4 + 1][kr] = f2b(v.y);
        T[n4 + 2][kr] = f2b(v.z);
        T[n4 + 3][kr] = f2b(v.w);
    }
    __syncthreads();
#pragma unroll
    for (int s = 0; s < 2; ++s) {
        const int lin = tid + 256 * s;
        const int n = lin >> 3;
        const int kc = (lin & 7) << 3;
        ushort4 a, b;
        a.x = T[n][kc + 0]; a.y = T[n][kc + 1]; a.z = T[n][kc + 2]; a.w = T[n][kc + 3];
        b.x = T[n][kc + 4]; b.y = T[n][kc + 5]; b.z = T[n][kc + 6]; b.w = T[n][kc + 7];
        ushort* p = &dst[(size_t)(n0 + n) * K + k0 + kc];
        *reinterpret_cast<ushort4*>(p) = a;
        *reinterpret_cast<ushort4*>(p + 4) = b;
    }
}

// ---------------- tiled GEMM (m97 structure): C = A[M][K] * Bt[N][K]^T ----------------
// ROUTE=1 (QKV fused, N=1536): grp0/1 (Q,K) -> l2norm rows (per head=wave's 64 cols)
// then bf16 to C0/C1; grp2 (V) -> direct transposed write to C2 = Vt[32][64][2048].
template <int F32OUT, int ROUTE>
__global__ __launch_bounds__(256)
void gemm_tile_k(const ushort* __restrict__ A, const ushort* __restrict__ Bt,
                 void* __restrict__ C0, void* __restrict__ C1, void* __restrict__ C2,
                 int M, int N, int K, int nby) {
    __shared__ __align__(16) ushort As[128 * 32];
    __shared__ __align__(16) ushort Bs[128 * 32];
    const int tid = threadIdx.x;
    const int lane = tid & 63;
    const int w = tid >> 6;
    const int l15 = lane & 15, g = lane >> 4;
    const int wr = w >> 1, wc = w & 1;

    const int nwg = gridDim.x;
    const int cpx = nwg >> 3;
    const int bid = blockIdx.x;
    const int swz = (bid & 7) * cpx + (bid >> 3);
    const int bx = swz / nby, by = swz - bx * nby;
    const int rbase = bx * 128, cbase = by * 128;

    const int srow = lane >> 2;
    const int scol = (lane & 3) * 8;
    const ushort* Aw0 = A + (size_t)(rbase + 32 * w + srow) * K + scol;
    const ushort* Bw0 = Bt + (size_t)(cbase + 32 * w + srow) * K + scol;

    f32x4 acc[4][4];
#pragma unroll
    for (int m = 0; m < 4; ++m)
#pragma unroll
        for (int n = 0; n < 4; ++n) acc[m][n] = (f32x4){0, 0, 0, 0};

    const int nk = K >> 5;
    for (int kt = 0; kt < nk; ++kt) {
        const int k0 = kt << 5;
        if (kt) __syncthreads();
        gload_lds16(Aw0 + k0,          &As[(32 * w) * 32]);
        gload_lds16(Aw0 + 16 * K + k0, &As[(32 * w + 16) * 32]);
        gload_lds16(Bw0 + k0,          &Bs[(32 * w) * 32]);
        gload_lds16(Bw0 + 16 * K + k0, &Bs[(32 * w + 16) * 32]);
        __syncthreads();
        bf16x8 af[4], bf[4];
#pragma unroll
        for (int m = 0; m < 4; ++m)
            af[m] = *reinterpret_cast<const bf16x8*>(&As[(64 * wr + 16 * m + l15) * 32 + 8 * g]);
#pragma unroll
        for (int n = 0; n < 4; ++n)
            bf[n] = *reinterpret_cast<const bf16x8*>(&Bs[(64 * wc + 16 * n + l15) * 32 + 8 * g]);
#pragma unroll
        for (int m = 0; m < 4; ++m)
#pragma unroll
            for (int n = 0; n < 4; ++n)
                acc[m][n] = MFMA16(af[m], bf[n], acc[m][n]);
    }

    if (ROUTE) {
        const int col0 = cbase + 64 * wc;     // wave-uniform, 64-aligned => one head
        const int grp = col0 >> 9;            // 0=Q,1=K,2=V
        const int co0 = col0 & 511;
        if (grp == 2) {
            // V: write transposed into Vt[32][64][2048]
            const int h = co0 >> 6;
#pragma unroll
            for (int m = 0; m < 4; ++m) {
                const int row = rbase + 64 * wr + 16 * m + 4 * g;
                const int bb = row >> 11;
                const int tok = row & 2047;
#pragma unroll
                for (int n = 0; n < 4; ++n) {
                    const int d = 16 * n + l15;
                    bf16x4 wv;
#pragma unroll
                    for (int r = 0; r < 4; ++r) wv[r] = (__bf16)acc[m][n][r];
                    ushort* dst = (ushort*)C2 + (((size_t)(bb * 8 + h) * 64 + d) * 2048 + tok);
                    *reinterpret_cast<bf16x4*>(dst) = wv;
                }
            }
        } else {
            // Q or K: l2-normalize each row over this head's 64 cols, write bf16
            ushort* Cg = (ushort*)(grp == 0 ? C0 : C1);
#pragma unroll
            for (int m = 0; m < 4; ++m) {
                f32x4 ss = {0, 0, 0, 0};
#pragma unroll
                for (int n = 0; n < 4; ++n)
#pragma unroll
                    for (int r = 0; r < 4; ++r) ss[r] += acc[m][n][r] * acc[m][n][r];
#pragma unroll
                for (int r = 0; r < 4; ++r) {
                    float s = ss[r];
                    s += __shfl_xor(s, 1);
                    s += __shfl_xor(s, 2);
                    s += __shfl_xor(s, 4);
                    s += __shfl_xor(s, 8);
                    ss[r] = 1.0f / fmaxf(sqrtf(s), 1e-12f);
                }
                const int row = rbase + 64 * wr + 16 * m + 4 * g;
#pragma unroll
                for (int n = 0; n < 4; ++n) {
                    const int co = co0 + 16 * n + l15;
#pragma unroll
                    for (int r = 0; r < 4; ++r)
                        Cg[(size_t)(row + r) * 512 + co] = f2b(acc[m][n][r] * ss[r]);
                }
            }
        }
    } else {
#pragma unroll
        for (int m = 0; m < 4; ++m)
#pragma unroll
            for (int n = 0; n < 4; ++n) {
                const int row = rbase + 64 * wr + 16 * m + 4 * g;
                const int col = cbase + 64 * wc + 16 * n + l15;
                if (F32OUT) {
#pragma unroll
                    for (int r = 0; r < 4; ++r)
                        reinterpret_cast<float*>(C0)[(size_t)(row + r) * N + col] = acc[m][n][r];
                } else {
#pragma unroll
                    for (int r = 0; r < 4; ++r)
                        reinterpret_cast<ushort*>(C0)[(size_t)(row + r) * N + col] = f2b(acc[m][n][r]);
                }
            }
    }
}

// ---------------- causal cosine-sim flash attention (v4: 2-wave blocks, balanced) ----------------
// 2 waves/block share K/V 64x64 LDS tiles (global_load_lds + 16B-chunk XOR swizzle,
// both-sides). Wave handles q-tiles (c, 127-c); fixed softmax offset 8.
// Grid (32 bh, 32 j); ytrue remap balances per-CU step totals; 4 blocks/CU.
__global__ __launch_bounds__(128, 2)
void flash_attn_k(const ushort* __restrict__ Q, const ushort* __restrict__ K,
                  const ushort* __restrict__ Vt, ushort* __restrict__ O) {
    __shared__ __align__(16) ushort Ks[64 * 64];
    __shared__ __align__(16) ushort Vs[64 * 64];
    const int tid = threadIdx.x;      // 0..127
    const int lane = tid & 63;
    const int wave = tid >> 6;
    const int l15 = lane & 15;
    const int g = lane >> 4;
    const int bh = blockIdx.x;
    const int b = bh >> 3, h = bh & 7;
    const int j = blockIdx.y;                   // 0..31
    const int ytrue = (j < 16) ? j : 47 - j;    // balance remap
    const int wglob = ytrue * 2 + wave;         // 0..63
    const int c0 = wglob;
    const int c1 = 127 - wglob;
    const int q0 = c0 * 16 + l15;
    const int q1 = c1 * 16 + l15;
    const int nt0 = (c0 * 16 + 79) >> 6;
    const int nt1 = (c1 * 16 + 79) >> 6;
    const int ntb = ((127 - 2 * ytrue) * 16 + 79) >> 6;  // block max (wave 0)

    const ushort* Qb = Q + (size_t)(b * 2048) * 512 + h * 64;
    const ushort* Kb = K + (size_t)(b * 2048) * 512 + h * 64;
    const ushort* Vb = Vt + (size_t)bh * 64 * 2048;

    // staging: tile = 512 x 16B chunks; wave w instr i covers chunks [w*64+128i, +64)
    // thread's chunk for instr i: s = tid + 128*i; row=s>>3, cc=s&7(=tid&7); src chunk = cc^(row&7)
    const ushort* kSrc[4];
    const ushort* vSrc[4];
    ushort* kDst[4];
    ushort* vDst[4];
#pragma unroll
    for (int i = 0; i < 4; ++i) {
        const int s = tid + 128 * i;
        const int row = s >> 3;
        const int cc = s & 7;
        const int sc = cc ^ (row & 7);
        kSrc[i] = Kb + (size_t)row * 512 + sc * 8;
        vSrc[i] = Vb + (size_t)row * 2048 + sc * 8;
        const int base = (wave * 64 + 128 * i) * 8;
        kDst[i] = &Ks[base];
        vDst[i] = &Vs[base];
    }

    bf16x8 qf0[2], qf1[2];
#pragma unroll
    for (int kh = 0; kh < 2; ++kh) {
        qf0[kh] = *reinterpret_cast<const bf16x8*>(Qb + (size_t)q0 * 512 + 32 * kh + 8 * g);
        qf1[kh] = *reinterpret_cast<const bf16x8*>(Qb + (size_t)q1 * 512 + 32 * kh + 8 * g);
    }

    f32x4 acc0[4], acc1[4];
#pragma unroll
    for (int d = 0; d < 4; ++d) {
        acc0[d] = (f32x4){0, 0, 0, 0};
        acc1[d] = (f32x4){0, 0, 0, 0};
    }
    float ls0 = 0.0f, ls1 = 0.0f;

    for (int t = 0; t < ntb; ++t) {
        if (t) __syncthreads();
#pragma unroll
        for (int i = 0; i < 4; ++i) gload_lds16(kSrc[i] + (size_t)t * 32768, kDst[i]);
#pragma unroll
        for (int i = 0; i < 4; ++i) gload_lds16(vSrc[i] + t * 64, vDst[i]);
        __syncthreads();

        if (t >= nt1) continue;
        const bool act0 = (t < nt0);
        const bool mk0 = (t == nt0 - 1);
        const bool mk1 = (t == nt1 - 1);

        bf16x8 af[4][2];
#pragma unroll
        for (int jt = 0; jt < 4; ++jt)
#pragma unroll
            for (int kh = 0; kh < 2; ++kh) {
                const int row = jt * 16 + l15;
                const int chunk = (g + 4 * kh) ^ (row & 7);
                af[jt][kh] = *reinterpret_cast<const bf16x8*>(&Ks[row * 64 + chunk * 8]);
            }
        bf16x4 vf[4][2][2];
#pragma unroll
        for (int d = 0; d < 4; ++d)
#pragma unroll
            for (int kk = 0; kk < 2; ++kk)
#pragma unroll
                for (int th = 0; th < 2; ++th) {
                    const int dr = d * 16 + l15;
                    const int chunk = ((g >> 1) + 2 * th + 4 * kk) ^ (dr & 7);
                    vf[d][kk][th] = *reinterpret_cast<const bf16x4*>(
                        &Vs[dr * 64 + chunk * 8 + (g & 1) * 4]);
                }

        f32x4 s1[4];
#pragma unroll
        for (int jt = 0; jt < 4; ++jt) {
            f32x4 z = {0, 0, 0, 0};
            z = MFMA16(af[jt][0], qf1[0], z);
            s1[jt] = MFMA16(af[jt][1], qf1[1], z);
        }

        bf16x8 pt1[2];
        float la1 = 0.0f;
#pragma unroll
        for (int jt = 0; jt < 4; ++jt) {
#pragma unroll
            for (int r = 0; r < 4; ++r) {
                float p = __expf(fmaf(s1[jt][r], 8.0f, -8.0f));
                if (mk1) {
                    int jj = t * 64 + jt * 16 + 4 * g + r;
                    p = (jj <= q1) ? p : 0.0f;
                }
                la1 += p;
                pt1[jt >> 1][(jt & 1) * 4 + r] = (__bf16)p;
            }
        }
        ls1 += la1;

#pragma unroll
        for (int d = 0; d < 4; ++d) {
            bf16x8 v0 = cat44(vf[d][0][0], vf[d][0][1]);
            bf16x8 v1 = cat44(vf[d][1][0], vf[d][1][1]);
            acc1[d] = MFMA16(v0, pt1[0], acc1[d]);
            acc1[d] = MFMA16(v1, pt1[1], acc1[d]);
        }

        if (act0) {
            f32x4 s0[4];
#pragma unroll
            for (int jt = 0; jt < 4; ++jt) {
                f32x4 z = {0, 0, 0, 0};
                z = MFMA16(af[jt][0], qf0[0], z);
                s0[jt] = MFMA16(af[jt][1], qf0[1], z);
            }
            bf16x8 pt0[2];
            float la0 = 0.0f;
#pragma unroll
            for (int jt = 0; jt < 4; ++jt) {
#pragma unroll
                for (int r = 0; r < 4; ++r) {
                    float p = __expf(fmaf(s0[jt][r], 8.0f, -8.0f));
                    if (mk0) {
                        int jj = t * 64 + jt * 16 + 4 * g + r;
                        p = (jj <= q0) ? p : 0.0f;
                    }
                    la0 += p;
                    pt0[jt >> 1][(jt & 1) * 4 + r] = (__bf16)p;
                }
            }
            ls0 += la0;
#pragma unroll
            for (int d = 0; d < 4; ++d) {
                bf16x8 v0 = cat44(vf[d][0][0], vf[d][0][1]);
                bf16x8 v1 = cat44(vf[d][1][0], vf[d][1][1]);
                acc0[d] = MFMA16(v0, pt0[0], acc0[d]);
                acc0[d] = MFMA16(v1, pt0[1], acc0[d]);
            }
        }
    }

    auto fin = [&](f32x4 (&acc)[4], float ls, int qr) {
        ls += __shfl_xor(ls, 16);
        ls += __shfl_xor(ls, 32);
        float inv = 1.0f / ls;
        ushort* Ob = O + (size_t)(b * 2048 + qr) * 512 + h * 64;
#pragma unroll
        for (int d = 0; d < 4; ++d) {
            bf16x4 w;
#pragma unroll
            for (int r = 0; r < 4; ++r) w[r] = (__bf16)(acc[d][r] * inv);
            *reinterpret_cast<bf16x4*>(Ob + d * 16 + 4 * g) = w;
        }
    };
    fin(acc1, ls1, q1);
    fin(acc0, ls0, q0);
}

extern "C" void kernel_launch(void* const* d_in, const int* in_sizes, int n_in,
                              void* d_out, int out_size, void* d_ws, size_t ws_size,
                              hipStream_t stream) {
    const float* x  = (const float*)d_in[0];
    const float* Wq = (const float*)d_in[1];
    const float* Wk = (const float*)d_in[2];
    const float* Wv = (const float*)d_in[3];
    const float* Wo = (const float*)d_in[4];
    float* out = (float*)d_out;

    char* ws = (char*)d_ws;
    ushort* xb  = (ushort*)ws; ws += (size_t)8192 * 1024 * 2;   // 16 MB
    ushort* Wqt = (ushort*)ws; ws += (size_t)1536 * 1024 * 2;   // fused [1536][1024]
    ushort* Wot = (ushort*)ws; ws += (size_t)1024 * 512 * 2;
    ushort* Qm  = (ushort*)ws; ws += (size_t)8192 * 512 * 2;
    ushort* Km  = (ushort*)ws; ws += (size_t)8192 * 512 * 2;
    ushort* Vtm = (ushort*)ws; ws += (size_t)8192 * 512 * 2;
    ushort* Om  = xb;  // reuse: xb dead after QKV GEMM

    f32_to_bf16_k<<<8192, 256, 0, stream>>>(x, xb, 2097152);
    transpose_all_k<<<512, 256, 0, stream>>>(Wq, Wk, Wv, Wo, Wqt, Wot);

    // fused QKV GEMM + l2norm(Q,K) + V transpose: -> Qm | Km | Vtm
    gemm_tile_k<0, 1><<<768, 256, 0, stream>>>(xb, Wqt, Qm, Km, Vtm, 8192, 1536, 1024, 12);

    flash_attn_k<<<dim3(32, 32), 128, 0, stream>>>(Qm, Km, Vtm, Om);

    // out projection: [8192][512] x [1024][512]^T -> out (f32)
    gemm_tile_k<1, 0><<<512, 256, 0, stream>>>(Om, Wot, out, nullptr, nullptr, 8192, 1024, 512, 8);
}